// Round 9
// baseline (65.458 us; speedup 1.0000x reference)
//
#include <hip/hip_runtime.h>
#include <stdint.h>

// LearnedTripleConnect: B=8,N=8192,S=8,D=64. out[b,n] = mean_s( gelu([xi|xj|xk]W1+b1) ) W2 + b2
// Round 9: algebraic split. P[n] = [A|V1|V2] = x[n]@[W1a|W1b|W1c] (+b1 on A), fp16, 50MB ws.
// Main kernel: z(n,s) = A[n] + V1[j] + V2[k] -> gelu -> mean_s -> GEMM2. GEMM1 eliminated.

typedef short  short8 __attribute__((ext_vector_type(8)));
typedef float  f32x2  __attribute__((ext_vector_type(2)));
typedef float  f32x4  __attribute__((ext_vector_type(4)));
typedef float  f32x16 __attribute__((ext_vector_type(16)));
typedef _Float16 h16x2 __attribute__((ext_vector_type(2)));

__device__ __forceinline__ unsigned short f2bf(float f){
  union { float f; unsigned u; } a; a.f = f;
  unsigned u = a.u;
  u += 0x7fffu + ((u >> 16) & 1u);   // RNE
  return (unsigned short)(u >> 16);
}
__device__ __forceinline__ f32x2 gelu2(f32x2 x){
  f32x2 x2 = x * x;
  f32x2 t  = x2 * (-0.1029437f) + (-2.3022083f);
  f32x2 xt = x * t;
  f32x2 r;
  r[0] = __builtin_amdgcn_rcpf(1.0f + __builtin_amdgcn_exp2f(xt[0]));
  r[1] = __builtin_amdgcn_rcpf(1.0f + __builtin_amdgcn_exp2f(xt[1]));
  return x * r;
}

// ---------------- prep: W' (64x384) MFMA B-frags + W2 frags ----------------
// w1f frag f = cb*4 + t (cb 0..11, t 0..3): lane l elem j = W1[(cb>>2)*64 + t*16 + 8*(l>>5)+j][ (cb&3)*32 + (l&31) ]
// w2f frag g = w*4 + q: lane l elem j = W2[(q*32 + 8*(l>>4)+j)*64 + w*16 + (l&15)]
__global__ void prep_w(const float* __restrict__ W1, const float* __restrict__ W2,
                       short* __restrict__ w1f, short* __restrict__ w2f){
  int t0 = threadIdx.x;
  for (int c = t0; c < 48 * 64; c += 256){
    int lane = c & 63, f = c >> 6;
    int cb = f >> 2, t = f & 3;
    short8 v;
    #pragma unroll
    for (int j = 0; j < 8; j++)
      v[j] = (short)f2bf(W1[((cb >> 2) * 64 + t * 16 + 8 * (lane >> 5) + j) * 128
                            + (cb & 3) * 32 + (lane & 31)]);
    *(short8*)(w1f + (long)c * 8) = v;
  }
  for (int c = t0; c < 16 * 64; c += 256){
    int lane = c & 63, g = c >> 6;
    int w = g >> 2, q = g & 3;
    short8 v;
    #pragma unroll
    for (int j = 0; j < 8; j++)
      v[j] = (short)f2bf(W2[(q * 32 + 8 * (lane >> 4) + j) * 64 + w * 16 + (lane & 15)]);
    *(short8*)(w2f + (long)c * 8) = v;
  }
}

// ---------------- P-GEMM: P[65536][384] fp16 = x(f32->bf16) @ W' ----------------
// batch-affine: bid&7 = batch -> rows written by the XCD that will gather them.
__global__ __launch_bounds__(256, 4) void pgemm(
    const float* __restrict__ x, const short* __restrict__ w1f,
    const float* __restrict__ b1, _Float16* __restrict__ P)
{
  const int tid = threadIdx.x;
  const int w = tid >> 6, lane = tid & 63;
  const int l31 = lane & 31, hi = lane >> 5;
  const int bid = blockIdx.x;
  const int n0 = (bid & 7) * 8192 + (bid >> 3) * 32;

  // A-frags: 32 rows x K=64, bf16
  short8 af[4];
  #pragma unroll
  for (int t = 0; t < 4; t++){
    const float* xr = x + (long)(n0 + l31) * 64 + t * 16 + 8 * hi;
    float4 a = *(const float4*)xr;
    float4 b = *(const float4*)(xr + 4);
    short8 v;
    v[0]=(short)f2bf(a.x); v[1]=(short)f2bf(a.y); v[2]=(short)f2bf(a.z); v[3]=(short)f2bf(a.w);
    v[4]=(short)f2bf(b.x); v[5]=(short)f2bf(b.y); v[6]=(short)f2bf(b.z); v[7]=(short)f2bf(b.w);
    af[t] = v;
  }

  #pragma unroll
  for (int ci = 0; ci < 3; ci++){
    const int cb = w * 3 + ci;
    float binit = (cb < 4) ? b1[cb * 32 + l31] : 0.0f;
    f32x16 acc;
    #pragma unroll
    for (int r = 0; r < 16; r++) acc[r] = binit;
    #pragma unroll
    for (int t = 0; t < 4; t++){
      short8 bf = *(const short8*)(w1f + (long)((cb * 4 + t) * 64 + lane) * 8);
      acc = __builtin_amdgcn_mfma_f32_32x32x16_bf16(af[t], bf, acc, 0, 0, 0);
    }
    _Float16* pb = P + (long)n0 * 384 + cb * 32 + l31;
    #pragma unroll
    for (int r = 0; r < 16; r++){
      int row = (r & 3) + 8 * (r >> 2) + 4 * hi;
      pb[(long)row * 384] = (_Float16)acc[r];
    }
  }
}

// ---------------- main: gather P + gelu + mean_s + GEMM2 ----------------
#define NT2 8   // 8-n tiles per block (64 n per block)
__global__ __launch_bounds__(256, 4) void ltc_main(
    const _Float16* __restrict__ P, const short* __restrict__ w2f,
    const int* __restrict__ jidx,   const int* __restrict__ kidx,
    const float* __restrict__ b2,   float* __restrict__ out)
{
  __shared__ short HB[2][8 * 136];   // hbar ping-pong: 8 n-rows x 128 h (bf16), stride 136

  const int tid  = threadIdx.x;
  const int w    = tid >> 6, lane = tid & 63;
  const int l15  = lane & 15, q4 = lane >> 4;

  short8 w2v[4];
  #pragma unroll
  for (int q = 0; q < 4; q++)
    w2v[q] = *(const short8*)(w2f + (long)((w * 4 + q) * 64 + lane) * 8);
  const float b2v = b2[w * 16 + l15];

  const int bid   = blockIdx.x;
  const int batch = bid & 7;
  const int gbase = batch * 8192 + (bid >> 3) * 64;   // first global n of this block
  const unsigned bb = (unsigned)(batch << 13);

  auto gemm2_store = [&](int hb, int ttp){
    f32x4 acc2 = {0.f, 0.f, 0.f, 0.f};
    #pragma unroll
    for (int q2 = 0; q2 < 4; q2++){
      short8 hbf = *(const short8*)((const char*)&HB[hb][0] + (l15 & 7) * 272 + q2 * 64 + q4 * 16);
      acc2 = __builtin_amdgcn_mfma_f32_16x16x32_bf16(hbf, w2v[q2], acc2, 0, 0, 0);
    }
    if (lane < 32){
      long NG = (long)(gbase + ttp * 8);
      #pragma unroll
      for (int r = 0; r < 4; r++)
        out[(NG + 4 * q4 + r) * 64 + w * 16 + l15] = acc2[r] + b2v;
    }
  };

  for (int tt = 0; tt < NT2; ++tt){
    asm volatile("s_waitcnt lgkmcnt(0)\n\ts_barrier" ::: "memory");  // HB[(tt-1)&1] published
    if (tt > 0) gemm2_store((tt ^ 1) & 1, tt - 1);

    #pragma unroll
    for (int u = 0; u < 2; u++){
      const int nn = tt * 8 + w * 2 + u;       // tile-local n (0..63)
      const int gn = gbase + nn;
      // indices for the 8 s-slots of this n
      const int4* jp = (const int4*)(jidx + (long)gn * 8);
      const int4* kp = (const int4*)(kidx + (long)gn * 8);
      int4 j0 = jp[0], j1 = jp[1];
      int4 k0 = kp[0], k1 = kp[1];
      int jv[8] = {j0.x, j0.y, j0.z, j0.w, j1.x, j1.y, j1.z, j1.w};
      int kv[8] = {k0.x, k0.y, k0.z, k0.w, k1.x, k1.y, k1.z, k1.w};

      // A (includes b1): 2 h per lane
      h16x2 av = *(const h16x2*)((const char*)P + (unsigned)gn * 768u + lane * 4u);
      f32x2 af; af[0] = (float)av[0]; af[1] = (float)av[1];

      f32x2 hs = {0.f, 0.f};
      #pragma unroll
      for (int s = 0; s < 8; s++){
        unsigned o1 = (bb + (unsigned)jv[s]) * 768u + 256u + lane * 4u;
        unsigned o2 = (bb + (unsigned)kv[s]) * 768u + 512u + lane * 4u;
        h16x2 v1 = *(const h16x2*)((const char*)P + o1);
        h16x2 v2 = *(const h16x2*)((const char*)P + o2);
        f32x2 z;
        z[0] = af[0] + (float)v1[0] + (float)v2[0];
        z[1] = af[1] + (float)v1[1] + (float)v2[1];
        hs += gelu2(z);
      }
      hs *= 0.125f;
      unsigned pk = (unsigned)f2bf(hs[0]) | ((unsigned)f2bf(hs[1]) << 16);
      *(unsigned*)&HB[tt & 1][(w * 2 + u) * 136 + lane * 2] = pk;
    }
  }

  asm volatile("s_waitcnt lgkmcnt(0)\n\ts_barrier" ::: "memory");
  gemm2_store((NT2 - 1) & 1, NT2 - 1);
}

// ---------------- fallback (ws too small): correct, slow ----------------
__global__ void ltc_naive(const float* __restrict__ x, const int* __restrict__ jidx,
                          const int* __restrict__ kidx, const float* __restrict__ W1,
                          const float* __restrict__ b1, const float* __restrict__ W2,
                          const float* __restrict__ b2, float* __restrict__ out)
{
  int gidx = blockIdx.x;            // b*8192+n
  int b = gidx >> 13;
  __shared__ float trip[8][192];
  __shared__ float hb[128];
  int t = threadIdx.x;              // 128
  for (int i = t; i < 8 * 192; i += 128){
    int s = i / 192, c = i - s * 192;
    int v = c >> 6, cc = c & 63;
    int src;
    if (v == 0)      src = gidx & 8191;
    else if (v == 1) src = jidx[gidx * 8 + s];
    else             src = kidx[gidx * 8 + s];
    trip[s][c] = x[((long)(b << 13) + src) * 64 + cc];
  }
  __syncthreads();
  float z[8];
  #pragma unroll
  for (int s = 0; s < 8; s++) z[s] = b1[t];
  for (int k = 0; k < 192; k++){
    float wv = W1[k * 128 + t];
    #pragma unroll
    for (int s = 0; s < 8; s++) z[s] = fmaf(trip[s][k], wv, z[s]);
  }
  float acc = 0.f;
  #pragma unroll
  for (int s = 0; s < 8; s++){
    f32x2 zz; zz[0] = z[s]; zz[1] = z[s];
    acc += gelu2(zz)[0];
  }
  hb[t] = acc * 0.125f;
  __syncthreads();
  if (t < 64){
    float o = b2[t];
    for (int h = 0; h < 128; h++) o = fmaf(hb[h], W2[h * 64 + t], o);
    out[(long)gidx * 64 + t] = o;
  }
}

extern "C" void kernel_launch(void* const* d_in, const int* in_sizes, int n_in,
                              void* d_out, int out_size, void* d_ws, size_t ws_size,
                              hipStream_t stream) {
  const float* x   = (const float*)d_in[0];
  const int*   jix = (const int*)  d_in[1];
  const int*   kix = (const int*)  d_in[2];
  const float* W1  = (const float*)d_in[3];
  const float* b1  = (const float*)d_in[4];
  const float* W2  = (const float*)d_in[5];
  const float* b2  = (const float*)d_in[6];
  float* out = (float*)d_out;

  const size_t w1f_elems = 48 * 64 * 8;                 // shorts
  const size_t w2f_elems = 16 * 64 * 8;
  const size_t p_elems   = (size_t)65536 * 384;         // fp16
  const size_t need = (w1f_elems + w2f_elems + p_elems) * 2;

  if (ws_size >= need){
    short*    w1f = (short*)d_ws;
    short*    w2f = w1f + w1f_elems;
    _Float16* P   = (_Float16*)(w2f + w2f_elems);
    prep_w<<<1, 256, 0, stream>>>(W1, W2, w1f, w2f);
    pgemm<<<2048, 256, 0, stream>>>(x, w1f, b1, P);
    ltc_main<<<1024, 256, 0, stream>>>(P, w2f, jix, kix, b2, out);
  } else {
    ltc_naive<<<8 * 8192, 128, 0, stream>>>(x, jix, kix, W1, b1, W2, b2, out);
  }
}